// Round 12
// baseline (224.369 us; speedup 1.0000x reference)
//
#include <hip/hip_runtime.h>
#include <math.h>

namespace {

typedef float v2f __attribute__((ext_vector_type(2)));

constexpr int B = 2;
constexpr int F = 4096;      // triangles per batch
constexpr int Q = 16384;     // points per batch
constexpr int NP = B * Q;    // 32768 total points
constexpr int BLOCK = 256;
constexpr int P4 = 4;        // points per lane in screen

// output layout in d_out (float32): dist [NP], closest [NP,3], faces [NP]
constexpr int OFF_DIST = 0;
constexpr int OFF_CP = NP;
constexpr int OFF_FACE = 4 * NP;

// ---------------- exact path (reference-bit-order, contract OFF) -----------

__device__ __forceinline__ float safediv(float num, float den) {
  #pragma clang fp contract(off)
  float d = (fabsf(den) > 1e-12f) ? den : 1.0f;
  return num / d;
}

__device__ __forceinline__ float clamp01(float x) {
  return fminf(fmaxf(x, 0.0f), 1.0f);
}

// Ericson region-based closest point on triangle, mirroring the JAX reference
// op-for-op (including the where/override order). Contract OFF inside.
__device__ __forceinline__ void closest_pt(
    float px, float py, float pz,
    float ax, float ay, float az,
    float bx, float by, float bz,
    float cx, float cy, float cz,
    float& rx, float& ry, float& rz) {
  #pragma clang fp contract(off)
  float abx = bx - ax, aby = by - ay, abz = bz - az;
  float acx = cx - ax, acy = cy - ay, acz = cz - az;
  float apx = px - ax, apy = py - ay, apz = pz - az;
  float d1 = (abx * apx + aby * apy) + abz * apz;
  float d2 = (acx * apx + acy * apy) + acz * apz;
  float bpx = px - bx, bpy = py - by, bpz = pz - bz;
  float d3 = (abx * bpx + aby * bpy) + abz * bpz;
  float d4 = (acx * bpx + acy * bpy) + acz * bpz;
  float cpx = px - cx, cpy = py - cy, cpz = pz - cz;
  float d5 = (abx * cpx + aby * cpy) + abz * cpz;
  float d6 = (acx * cpx + acy * cpy) + acz * cpz;

  float vc = d1 * d4 - d3 * d2;
  float vb = d5 * d2 - d1 * d6;
  float va = d3 * d6 - d5 * d4;

  float v_ab = clamp01(safediv(d1, d1 - d3));
  float w_ac = clamp01(safediv(d2, d2 - d6));
  float w_bc = clamp01(safediv(d4 - d3, (d4 - d3) + (d5 - d6)));

  float denom = (va + vb) + vc;
  float v = safediv(vb, denom);
  float w = safediv(vc, denom);

  float ox = ax + abx * v + acx * w;
  float oy = ay + aby * v + acy * w;
  float oz = az + abz * v + acz * w;

  bool m_bc = (va <= 0.0f) && (d4 - d3 >= 0.0f) && (d5 - d6 >= 0.0f);
  bool m_ac = (vb <= 0.0f) && (d2 >= 0.0f) && (d6 <= 0.0f);
  bool m_ab = (vc <= 0.0f) && (d1 >= 0.0f) && (d3 <= 0.0f);
  bool m_c  = (d6 >= 0.0f) && (d5 <= d6);
  bool m_b  = (d3 >= 0.0f) && (d4 <= d3);
  bool m_a  = (d1 <= 0.0f) && (d2 <= 0.0f);

  if (m_bc) { ox = bx + w_bc * (cx - bx); oy = by + w_bc * (cy - by); oz = bz + w_bc * (cz - bz); }
  if (m_ac) { ox = ax + w_ac * acx;       oy = ay + w_ac * acy;       oz = az + w_ac * acz; }
  if (m_ab) { ox = ax + v_ab * abx;       oy = ay + v_ab * aby;       oz = az + v_ab * abz; }
  if (m_c)  { ox = cx; oy = cy; oz = cz; }
  if (m_b)  { ox = bx; oy = by; oz = bz; }
  if (m_a)  { ox = ax; oy = ay; oz = az; }

  rx = ox; ry = oy; rz = oz;
}

__device__ __forceinline__ float exact_d2(
    float px, float py, float pz, const float* __restrict__ g /*a,b,c*/) {
  #pragma clang fp contract(off)
  float rx, ry, rz;
  closest_pt(px, py, pz,
             g[0], g[1], g[2], g[3], g[4], g[5], g[6], g[7], g[8],
             rx, ry, rz);
  float dx = px - rx, dy = py - ry, dz = pz - rz;
  return (dx * dx + dy * dy) + dz * dz;
}

// ---------------- key helpers ----------------------------------------------

__device__ __forceinline__ unsigned umin2(unsigned a, unsigned b) { return a < b ? a : b; }
__device__ __forceinline__ unsigned umax2(unsigned a, unsigned b) { return a > b ? a : b; }

// sorted top-2 insert via min/max (3 VOP2 ops)
__device__ __forceinline__ void ins2(unsigned k, unsigned& K1, unsigned& K2) {
  unsigned t = umax2(K1, k);
  K1 = umin2(K1, k);
  K2 = umin2(K2, t);
}

// sorted top-8 insert via min/max network
__device__ __forceinline__ void ins8(unsigned k,
    unsigned& K1, unsigned& K2, unsigned& K3, unsigned& K4,
    unsigned& K5, unsigned& K6, unsigned& K7, unsigned& K8) {
  unsigned t;
  t = umax2(K1, k); K1 = umin2(K1, k);
  k = t; t = umax2(K2, k); K2 = umin2(K2, k);
  k = t; t = umax2(K3, k); K3 = umin2(K3, k);
  k = t; t = umax2(K4, k); K4 = umin2(K4, k);
  k = t; t = umax2(K5, k); K5 = umin2(K5, k);
  k = t; t = umax2(K6, k); K6 = umin2(K6, k);
  k = t; t = umax2(K7, k); K7 = umin2(K7, k);
  K8 = umin2(K8, t);
}

// scalar finish of one point's screen value: returns packed key
__device__ __forceinline__ unsigned fin_one(
    float dint, float tabm, float tacm, float tbcm,
    float td1, float td2, float ap2m, float bp2, float t43d,
    float va, float vb, float vc,
    float aa, float bb, float cc, float pp, int gidx) {
  float tab = __builtin_amdgcn_fmed3f(tabm, 0.0f, 1.0f);
  float sab = fmaf(-tab, fmaf(-tab, aa, td1), ap2m);
  float tac = __builtin_amdgcn_fmed3f(tacm, 0.0f, 1.0f);
  float sac = fmaf(-tac, fmaf(-tac, bb, td2), ap2m);
  float tbc = __builtin_amdgcn_fmed3f(tbcm, 0.0f, 1.0f);
  float sbc = fmaf(-tbc, fmaf(-tbc, cc, t43d), bp2);
  float dseg = fminf(fminf(sab, sac), sbc);        // v_min3
  float mv   = fminf(fminf(va, vb), vc);           // v_min3
  float d = (mv > 0.0f) ? dint : dseg;
  d = fmaxf(d + pp, 0.0f);                         // restore |p|^2, keep >=0
  return (__float_as_uint(d) & 0xFFFFF000u) | (unsigned)gidx;
}

// ---------------- screen: LDS records, P=4 points/lane ---------------------
// LDS record (20 floats = 5 quads):
//  R0=[abx,aby,abz,c1] R1=[acx,acy,acz,c2] R2=[-2ax,-2ay,-2az,|a|^2]
//  R3=[aa,bb,abac,cc]  R4=[raa,rbb,rcc,rdn]

template <int NC, int WPE>
__global__ __launch_bounds__(BLOCK, WPE) void bvh_screen4(
    const float* __restrict__ tris,   // [B, F, 3, 3]
    const float* __restrict__ pts,    // [B, Q, 3]
    uint2* __restrict__ keys) {       // [NC, NP]
  constexpr int CFL = F / NC;
  __shared__ float4 s_rec[5 * CFL];

  constexpr int BPB = (Q / P4) / BLOCK;          // 16
  const int batch = blockIdx.x / BPB;            // uniform per block
  const int j = (blockIdx.x % BPB) * BLOCK + threadIdx.x;  // 0 .. Q/4-1
  const int chunk = blockIdx.y;
  const int tri0 = chunk * CFL;
  const float* tb = tris + (size_t)batch * F * 9;

  for (int t = threadIdx.x; t < CFL; t += BLOCK) {
    const float* g = tb + (size_t)(tri0 + t) * 9;
    float ax = g[0], ay = g[1], az = g[2];
    float abx = g[3] - ax, aby = g[4] - ay, abz = g[5] - az;
    float acx = g[6] - ax, acy = g[7] - ay, acz = g[8] - az;
    float aa   = abx * abx + aby * aby + abz * abz;
    float bb   = acx * acx + acy * acy + acz * acz;
    float abac = abx * acx + aby * acy + abz * acz;
    float bcx = acx - abx, bcy = acy - aby, bcz = acz - abz;
    float cc   = bcx * bcx + bcy * bcy + bcz * bcz;
    float nx = aby * acz - abz * acy;
    float ny = abz * acx - abx * acz;
    float nz = abx * acy - aby * acx;
    float n2 = nx * nx + ny * ny + nz * nz;
    float raa = (aa > 1e-12f) ? 1.0f / aa : 1.0f;     // safediv-style guards
    float rbb = (bb > 1e-12f) ? 1.0f / bb : 1.0f;
    float rcc = (cc > 1e-12f) ? 1.0f / cc : 1.0f;
    float rdn = (n2 > 1e-12f) ? 1.0f / n2 : 1.0f;
    float c1 = -(ax * abx + ay * aby + az * abz);
    float c2 = -(ax * acx + ay * acy + az * acz);
    float caa2 = ax * ax + ay * ay + az * az;
    s_rec[0 * CFL + t] = make_float4(abx, aby, abz, c1);
    s_rec[1 * CFL + t] = make_float4(acx, acy, acz, c2);
    s_rec[2 * CFL + t] = make_float4(-2.0f * ax, -2.0f * ay, -2.0f * az, caa2);
    s_rec[3 * CFL + t] = make_float4(aa, bb, abac, cc);
    s_rec[4 * CFL + t] = make_float4(raa, rbb, rcc, rdn);
  }
  __syncthreads();

  const int p0 = batch * Q + j;
  float px0 = pts[(p0          ) * 3 + 0], py0 = pts[(p0          ) * 3 + 1], pz0 = pts[(p0          ) * 3 + 2];
  float px1 = pts[(p0 + Q/4    ) * 3 + 0], py1 = pts[(p0 + Q/4    ) * 3 + 1], pz1 = pts[(p0 + Q/4    ) * 3 + 2];
  float px2 = pts[(p0 + Q/2    ) * 3 + 0], py2 = pts[(p0 + Q/2    ) * 3 + 1], pz2 = pts[(p0 + Q/2    ) * 3 + 2];
  float px3 = pts[(p0 + 3*(Q/4)) * 3 + 0], py3 = pts[(p0 + 3*(Q/4)) * 3 + 1], pz3 = pts[(p0 + 3*(Q/4)) * 3 + 2];

  const v2f pxA = {px0, px1}, pyA = {py0, py1}, pzA = {pz0, pz1};
  const v2f pxB = {px2, px3}, pyB = {py2, py3}, pzB = {pz2, pz3};
  const float pp0 = px0*px0 + py0*py0 + pz0*pz0;
  const float pp1 = px1*px1 + py1*py1 + pz1*pz1;
  const float pp2 = px2*px2 + py2*py2 + pz2*pz2;
  const float pp3 = px3*px3 + py3*py3 + pz3*pz3;

  unsigned A1 = ~0u, A2 = ~0u, Bk1 = ~0u, Bk2 = ~0u;
  unsigned C1 = ~0u, C2 = ~0u, D1 = ~0u, D2 = ~0u;

  {
    #pragma clang fp contract(fast)
    for (int t = 0; t < CFL; ++t) {
      const float4 R0 = s_rec[0 * CFL + t];   // uniform addr -> broadcast
      const float4 R1 = s_rec[1 * CFL + t];
      const float4 R2 = s_rec[2 * CFL + t];
      const float4 R3 = s_rec[3 * CFL + t];
      const float4 R4 = s_rec[4 * CFL + t];
      const int gidx = tri0 + t;
      {
        v2f d1   = pxA * R0.x + pyA * R0.y + pzA * R0.z + R0.w;
        v2f d2   = pxA * R1.x + pyA * R1.y + pzA * R1.z + R1.w;
        v2f ap2m = pxA * R2.x + pyA * R2.y + pzA * R2.z + R2.w;
        v2f d3 = d1 - R3.x, d6 = d2 - R3.y, d4 = d2 - R3.z, d5 = d1 - R3.z;
        v2f t43 = d4 - d3;
        v2f va = d3 * d6 - d5 * d4;
        v2f vb = d5 * d2 - d1 * d6;
        v2f vc = d1 * d4 - d3 * d2;
        v2f td1 = d1 + d1, td2 = d2 + d2;
        v2f v = vb * R4.w, w = vc * R4.w;
        v2f h1 = v * R3.x + (w * R3.z - td1);
        v2f h2 = w * R3.y + (v * R3.z - td2);
        v2f dint = ap2m + (v * h1 + w * h2);
        v2f tabm = d1 * R4.x, tacm = d2 * R4.y, tbcm = t43 * R4.z;
        v2f bp2 = (ap2m - td1) + R3.x;
        v2f t43d = t43 + t43;
        ins2(fin_one(dint.x, tabm.x, tacm.x, tbcm.x, td1.x, td2.x, ap2m.x,
                     bp2.x, t43d.x, va.x, vb.x, vc.x,
                     R3.x, R3.y, R3.w, pp0, gidx), A1, A2);
        ins2(fin_one(dint.y, tabm.y, tacm.y, tbcm.y, td1.y, td2.y, ap2m.y,
                     bp2.y, t43d.y, va.y, vb.y, vc.y,
                     R3.x, R3.y, R3.w, pp1, gidx), Bk1, Bk2);
      }
      {
        v2f d1   = pxB * R0.x + pyB * R0.y + pzB * R0.z + R0.w;
        v2f d2   = pxB * R1.x + pyB * R1.y + pzB * R1.z + R1.w;
        v2f ap2m = pxB * R2.x + pyB * R2.y + pzB * R2.z + R2.w;
        v2f d3 = d1 - R3.x, d6 = d2 - R3.y, d4 = d2 - R3.z, d5 = d1 - R3.z;
        v2f t43 = d4 - d3;
        v2f va = d3 * d6 - d5 * d4;
        v2f vb = d5 * d2 - d1 * d6;
        v2f vc = d1 * d4 - d3 * d2;
        v2f td1 = d1 + d1, td2 = d2 + d2;
        v2f v = vb * R4.w, w = vc * R4.w;
        v2f h1 = v * R3.x + (w * R3.z - td1);
        v2f h2 = w * R3.y + (v * R3.z - td2);
        v2f dint = ap2m + (v * h1 + w * h2);
        v2f tabm = d1 * R4.x, tacm = d2 * R4.y, tbcm = t43 * R4.z;
        v2f bp2 = (ap2m - td1) + R3.x;
        v2f t43d = t43 + t43;
        ins2(fin_one(dint.x, tabm.x, tacm.x, tbcm.x, td1.x, td2.x, ap2m.x,
                     bp2.x, t43d.x, va.x, vb.x, vc.x,
                     R3.x, R3.y, R3.w, pp2, gidx), C1, C2);
        ins2(fin_one(dint.y, tabm.y, tacm.y, tbcm.y, td1.y, td2.y, ap2m.y,
                     bp2.y, t43d.y, va.y, vb.y, vc.y,
                     R3.x, R3.y, R3.w, pp3, gidx), D1, D2);
      }
    }
  }

  keys[(size_t)chunk * NP + p0            ] = make_uint2(A1, A2);
  keys[(size_t)chunk * NP + p0 + Q/4      ] = make_uint2(Bk1, Bk2);
  keys[(size_t)chunk * NP + p0 + Q/2      ] = make_uint2(C1, C2);
  keys[(size_t)chunk * NP + p0 + 3*(Q/4)  ] = make_uint2(D1, D2);
}

// ---------------- finish: merge 2*NC keys -> top-8 -> exact ----------------

template <int NC>
__global__ __launch_bounds__(BLOCK) void bvh_finish2(
    const float* __restrict__ tris,
    const float* __restrict__ pts,
    const uint2* __restrict__ keys,
    float* __restrict__ out) {
  const int gpt = blockIdx.x * BLOCK + threadIdx.x;
  if (gpt >= NP) return;

  unsigned K1 = ~0u, K2 = ~0u, K3 = ~0u, K4 = ~0u;
  unsigned K5 = ~0u, K6 = ~0u, K7 = ~0u, K8 = ~0u;
  for (int c = 0; c < NC; ++c) {
    uint2 k = keys[(size_t)c * NP + gpt];
    ins8(k.x, K1, K2, K3, K4, K5, K6, K7, K8);
    ins8(k.y, K1, K2, K3, K4, K5, K6, K7, K8);
  }

  const int batch = gpt / Q;
  const float* tb = tris + (size_t)batch * F * 9;
  const float px = pts[gpt * 3 + 0];
  const float py = pts[gpt * 3 + 1];
  const float pz = pts[gpt * 3 + 2];

  // order-independent first-occurrence argmin over the 8 candidates
  float be = INFINITY;
  int bi = 0x7FFFFFFF;
  #define CAND(Kx) { int t_ = (int)(Kx & 0xFFFu); \
    float d_ = exact_d2(px, py, pz, tb + (size_t)t_ * 9); \
    if (d_ < be || (d_ == be && t_ < bi)) { be = d_; bi = t_; } }
  CAND(K1) CAND(K2) CAND(K3) CAND(K4) CAND(K5) CAND(K6) CAND(K7) CAND(K8)
  #undef CAND

  const float* tr = tb + (size_t)bi * 9;
  float rx, ry, rz;
  closest_pt(px, py, pz,
             tr[0], tr[1], tr[2], tr[3], tr[4], tr[5], tr[6], tr[7], tr[8],
             rx, ry, rz);

  out[OFF_DIST + gpt] = be;
  out[OFF_CP + gpt * 3 + 0] = rx;
  out[OFF_CP + gpt * 3 + 1] = ry;
  out[OFF_CP + gpt * 3 + 2] = rz;
  out[OFF_FACE + gpt] = (float)bi;
}

}  // namespace

extern "C" void kernel_launch(void* const* d_in, const int* in_sizes, int n_in,
                              void* d_out, int out_size, void* d_ws, size_t ws_size,
                              hipStream_t stream) {
  const float* tris = (const float*)d_in[0];
  const float* pts  = (const float*)d_in[1];
  float* out = (float*)d_out;

  dim3 grid2((NP + BLOCK - 1) / BLOCK);
  const int gx = B * ((Q / P4) / BLOCK);   // 32 blocks in x

  constexpr size_t KEY64_BYTES = (size_t)64 * NP * sizeof(uint2);  // 16 MiB
  constexpr size_t KEY32_BYTES = (size_t)32 * NP * sizeof(uint2);  //  8 MiB

  if (ws_size >= KEY64_BYTES) {
    // NC=64: 2048 blocks = 8/CU = 8 waves/SIMD (launch_bounds caps VGPR at 64)
    uint2* keys = (uint2*)d_ws;
    bvh_screen4<64, 8><<<dim3(gx, 64), BLOCK, 0, stream>>>(tris, pts, keys);
    bvh_finish2<64><<<grid2, BLOCK, 0, stream>>>(tris, pts, keys, out);
  } else {
    // round-10 proven path (8 MiB): NC=32, 4 blocks/CU
    uint2* keys = (uint2*)d_ws;
    bvh_screen4<32, 4><<<dim3(gx, 32), BLOCK, 0, stream>>>(tris, pts, keys);
    bvh_finish2<32><<<grid2, BLOCK, 0, stream>>>(tris, pts, keys, out);
  }
}

// Round 13
// 166.952 us; speedup vs baseline: 1.3439x; 1.3439x over previous
//
#include <hip/hip_runtime.h>
#include <math.h>

namespace {

typedef float v2f __attribute__((ext_vector_type(2)));

constexpr int B = 2;
constexpr int F = 4096;      // triangles per batch
constexpr int Q = 16384;     // points per batch
constexpr int NP = B * Q;    // 32768 total points
constexpr int BLOCK = 256;
constexpr int P4 = 4;        // points per lane in screen

// output layout in d_out (float32): dist [NP], closest [NP,3], faces [NP]
constexpr int OFF_DIST = 0;
constexpr int OFF_CP = NP;
constexpr int OFF_FACE = 4 * NP;

// ---------------- exact path (reference-bit-order, contract OFF) -----------

__device__ __forceinline__ float safediv(float num, float den) {
  #pragma clang fp contract(off)
  float d = (fabsf(den) > 1e-12f) ? den : 1.0f;
  return num / d;
}

__device__ __forceinline__ float clamp01(float x) {
  return fminf(fmaxf(x, 0.0f), 1.0f);
}

// Ericson region-based closest point on triangle, mirroring the JAX reference
// op-for-op (including the where/override order). Contract OFF inside.
__device__ __forceinline__ void closest_pt(
    float px, float py, float pz,
    float ax, float ay, float az,
    float bx, float by, float bz,
    float cx, float cy, float cz,
    float& rx, float& ry, float& rz) {
  #pragma clang fp contract(off)
  float abx = bx - ax, aby = by - ay, abz = bz - az;
  float acx = cx - ax, acy = cy - ay, acz = cz - az;
  float apx = px - ax, apy = py - ay, apz = pz - az;
  float d1 = (abx * apx + aby * apy) + abz * apz;
  float d2 = (acx * apx + acy * apy) + acz * apz;
  float bpx = px - bx, bpy = py - by, bpz = pz - bz;
  float d3 = (abx * bpx + aby * bpy) + abz * bpz;
  float d4 = (acx * bpx + acy * bpy) + acz * bpz;
  float cpx = px - cx, cpy = py - cy, cpz = pz - cz;
  float d5 = (abx * cpx + aby * cpy) + abz * cpz;
  float d6 = (acx * cpx + acy * cpy) + acz * cpz;

  float vc = d1 * d4 - d3 * d2;
  float vb = d5 * d2 - d1 * d6;
  float va = d3 * d6 - d5 * d4;

  float v_ab = clamp01(safediv(d1, d1 - d3));
  float w_ac = clamp01(safediv(d2, d2 - d6));
  float w_bc = clamp01(safediv(d4 - d3, (d4 - d3) + (d5 - d6)));

  float denom = (va + vb) + vc;
  float v = safediv(vb, denom);
  float w = safediv(vc, denom);

  float ox = ax + abx * v + acx * w;
  float oy = ay + aby * v + acy * w;
  float oz = az + abz * v + acz * w;

  bool m_bc = (va <= 0.0f) && (d4 - d3 >= 0.0f) && (d5 - d6 >= 0.0f);
  bool m_ac = (vb <= 0.0f) && (d2 >= 0.0f) && (d6 <= 0.0f);
  bool m_ab = (vc <= 0.0f) && (d1 >= 0.0f) && (d3 <= 0.0f);
  bool m_c  = (d6 >= 0.0f) && (d5 <= d6);
  bool m_b  = (d3 >= 0.0f) && (d4 <= d3);
  bool m_a  = (d1 <= 0.0f) && (d2 <= 0.0f);

  if (m_bc) { ox = bx + w_bc * (cx - bx); oy = by + w_bc * (cy - by); oz = bz + w_bc * (cz - bz); }
  if (m_ac) { ox = ax + w_ac * acx;       oy = ay + w_ac * acy;       oz = az + w_ac * acz; }
  if (m_ab) { ox = ax + v_ab * abx;       oy = ay + v_ab * aby;       oz = az + v_ab * abz; }
  if (m_c)  { ox = cx; oy = cy; oz = cz; }
  if (m_b)  { ox = bx; oy = by; oz = bz; }
  if (m_a)  { ox = ax; oy = ay; oz = az; }

  rx = ox; ry = oy; rz = oz;
}

__device__ __forceinline__ float exact_d2(
    float px, float py, float pz, const float* __restrict__ g /*a,b,c*/) {
  #pragma clang fp contract(off)
  float rx, ry, rz;
  closest_pt(px, py, pz,
             g[0], g[1], g[2], g[3], g[4], g[5], g[6], g[7], g[8],
             rx, ry, rz);
  float dx = px - rx, dy = py - ry, dz = pz - rz;
  return (dx * dx + dy * dy) + dz * dz;
}

// ---------------- key helpers ----------------------------------------------

__device__ __forceinline__ unsigned umin2(unsigned a, unsigned b) { return a < b ? a : b; }
__device__ __forceinline__ unsigned umax2(unsigned a, unsigned b) { return a > b ? a : b; }

// sorted top-2 insert via min/max (3 VOP2 ops)
__device__ __forceinline__ void ins2(unsigned k, unsigned& K1, unsigned& K2) {
  unsigned t = umax2(K1, k);
  K1 = umin2(K1, k);
  K2 = umin2(K2, t);
}

// sorted top-8 insert via min/max network
__device__ __forceinline__ void ins8(unsigned k,
    unsigned& K1, unsigned& K2, unsigned& K3, unsigned& K4,
    unsigned& K5, unsigned& K6, unsigned& K7, unsigned& K8) {
  unsigned t;
  t = umax2(K1, k); K1 = umin2(K1, k);
  k = t; t = umax2(K2, k); K2 = umin2(K2, k);
  k = t; t = umax2(K3, k); K3 = umin2(K3, k);
  k = t; t = umax2(K4, k); K4 = umin2(K4, k);
  k = t; t = umax2(K5, k); K5 = umin2(K5, k);
  k = t; t = umax2(K6, k); K6 = umin2(K6, k);
  k = t; t = umax2(K7, k); K7 = umin2(K7, k);
  K8 = umin2(K8, t);
}

// scalar finish of one point's screen value: returns packed key
__device__ __forceinline__ unsigned fin_one(
    float dint, float tabm, float tacm, float tbcm,
    float td1, float td2, float ap2m, float bp2, float t43d,
    float va, float vb, float vc,
    float aa, float bb, float cc, float pp, int gidx) {
  float tab = __builtin_amdgcn_fmed3f(tabm, 0.0f, 1.0f);
  float sab = fmaf(-tab, fmaf(-tab, aa, td1), ap2m);
  float tac = __builtin_amdgcn_fmed3f(tacm, 0.0f, 1.0f);
  float sac = fmaf(-tac, fmaf(-tac, bb, td2), ap2m);
  float tbc = __builtin_amdgcn_fmed3f(tbcm, 0.0f, 1.0f);
  float sbc = fmaf(-tbc, fmaf(-tbc, cc, t43d), bp2);
  float dseg = fminf(fminf(sab, sac), sbc);        // v_min3
  float mv   = fminf(fminf(va, vb), vc);           // v_min3
  float d = (mv > 0.0f) ? dint : dseg;
  d = fmaxf(d + pp, 0.0f);                         // restore |p|^2, keep >=0
  return (__float_as_uint(d) & 0xFFFFF000u) | (unsigned)gidx;
}

// ---------------- screen: LDS records, P=4 points/lane ---------------------
// LDS record (20 floats = 5 quads):
//  R0=[abx,aby,abz,c1] R1=[acx,acy,acz,c2] R2=[-2ax,-2ay,-2az,|a|^2]
//  R3=[aa,bb,abac,cc]  R4=[raa,rbb,rcc,rdn]

template <int NC, int WPE>
__global__ __launch_bounds__(BLOCK, WPE) void bvh_screen4(
    const float* __restrict__ tris,   // [B, F, 3, 3]
    const float* __restrict__ pts,    // [B, Q, 3]
    uint2* __restrict__ keys) {       // [NC, NP]
  constexpr int CFL = F / NC;
  __shared__ float4 s_rec[5 * CFL];

  constexpr int BPB = (Q / P4) / BLOCK;          // 16
  const int batch = blockIdx.x / BPB;            // uniform per block
  const int j = (blockIdx.x % BPB) * BLOCK + threadIdx.x;  // 0 .. Q/4-1
  const int chunk = blockIdx.y;
  const int tri0 = chunk * CFL;
  const float* tb = tris + (size_t)batch * F * 9;

  for (int t = threadIdx.x; t < CFL; t += BLOCK) {
    const float* g = tb + (size_t)(tri0 + t) * 9;
    float ax = g[0], ay = g[1], az = g[2];
    float abx = g[3] - ax, aby = g[4] - ay, abz = g[5] - az;
    float acx = g[6] - ax, acy = g[7] - ay, acz = g[8] - az;
    float aa   = abx * abx + aby * aby + abz * abz;
    float bb   = acx * acx + acy * acy + acz * acz;
    float abac = abx * acx + aby * acy + abz * acz;
    float bcx = acx - abx, bcy = acy - aby, bcz = acz - abz;
    float cc   = bcx * bcx + bcy * bcy + bcz * bcz;
    float nx = aby * acz - abz * acy;
    float ny = abz * acx - abx * acz;
    float nz = abx * acy - aby * acx;
    float n2 = nx * nx + ny * ny + nz * nz;
    float raa = (aa > 1e-12f) ? 1.0f / aa : 1.0f;     // safediv-style guards
    float rbb = (bb > 1e-12f) ? 1.0f / bb : 1.0f;
    float rcc = (cc > 1e-12f) ? 1.0f / cc : 1.0f;
    float rdn = (n2 > 1e-12f) ? 1.0f / n2 : 1.0f;
    float c1 = -(ax * abx + ay * aby + az * abz);
    float c2 = -(ax * acx + ay * acy + az * acz);
    float caa2 = ax * ax + ay * ay + az * az;
    s_rec[0 * CFL + t] = make_float4(abx, aby, abz, c1);
    s_rec[1 * CFL + t] = make_float4(acx, acy, acz, c2);
    s_rec[2 * CFL + t] = make_float4(-2.0f * ax, -2.0f * ay, -2.0f * az, caa2);
    s_rec[3 * CFL + t] = make_float4(aa, bb, abac, cc);
    s_rec[4 * CFL + t] = make_float4(raa, rbb, rcc, rdn);
  }
  __syncthreads();

  const int p0 = batch * Q + j;
  float px0 = pts[(p0          ) * 3 + 0], py0 = pts[(p0          ) * 3 + 1], pz0 = pts[(p0          ) * 3 + 2];
  float px1 = pts[(p0 + Q/4    ) * 3 + 0], py1 = pts[(p0 + Q/4    ) * 3 + 1], pz1 = pts[(p0 + Q/4    ) * 3 + 2];
  float px2 = pts[(p0 + Q/2    ) * 3 + 0], py2 = pts[(p0 + Q/2    ) * 3 + 1], pz2 = pts[(p0 + Q/2    ) * 3 + 2];
  float px3 = pts[(p0 + 3*(Q/4)) * 3 + 0], py3 = pts[(p0 + 3*(Q/4)) * 3 + 1], pz3 = pts[(p0 + 3*(Q/4)) * 3 + 2];

  const v2f pxA = {px0, px1}, pyA = {py0, py1}, pzA = {pz0, pz1};
  const v2f pxB = {px2, px3}, pyB = {py2, py3}, pzB = {pz2, pz3};
  const float pp0 = px0*px0 + py0*py0 + pz0*pz0;
  const float pp1 = px1*px1 + py1*py1 + pz1*pz1;
  const float pp2 = px2*px2 + py2*py2 + pz2*pz2;
  const float pp3 = px3*px3 + py3*py3 + pz3*pz3;

  unsigned A1 = ~0u, A2 = ~0u, Bk1 = ~0u, Bk2 = ~0u;
  unsigned C1 = ~0u, C2 = ~0u, D1 = ~0u, D2 = ~0u;

  {
    #pragma clang fp contract(fast)
    for (int t = 0; t < CFL; ++t) {
      const float4 R0 = s_rec[0 * CFL + t];   // uniform addr -> broadcast
      const float4 R1 = s_rec[1 * CFL + t];
      const float4 R2 = s_rec[2 * CFL + t];
      const float4 R3 = s_rec[3 * CFL + t];
      const float4 R4 = s_rec[4 * CFL + t];
      const int gidx = tri0 + t;
      {
        v2f d1   = pxA * R0.x + pyA * R0.y + pzA * R0.z + R0.w;
        v2f d2   = pxA * R1.x + pyA * R1.y + pzA * R1.z + R1.w;
        v2f ap2m = pxA * R2.x + pyA * R2.y + pzA * R2.z + R2.w;
        v2f d3 = d1 - R3.x, d6 = d2 - R3.y, d4 = d2 - R3.z, d5 = d1 - R3.z;
        v2f t43 = d4 - d3;
        v2f va = d3 * d6 - d5 * d4;
        v2f vb = d5 * d2 - d1 * d6;
        v2f vc = d1 * d4 - d3 * d2;
        v2f td1 = d1 + d1, td2 = d2 + d2;
        v2f v = vb * R4.w, w = vc * R4.w;
        v2f h1 = v * R3.x + (w * R3.z - td1);
        v2f h2 = w * R3.y + (v * R3.z - td2);
        v2f dint = ap2m + (v * h1 + w * h2);
        v2f tabm = d1 * R4.x, tacm = d2 * R4.y, tbcm = t43 * R4.z;
        v2f bp2 = (ap2m - td1) + R3.x;
        v2f t43d = t43 + t43;
        ins2(fin_one(dint.x, tabm.x, tacm.x, tbcm.x, td1.x, td2.x, ap2m.x,
                     bp2.x, t43d.x, va.x, vb.x, vc.x,
                     R3.x, R3.y, R3.w, pp0, gidx), A1, A2);
        ins2(fin_one(dint.y, tabm.y, tacm.y, tbcm.y, td1.y, td2.y, ap2m.y,
                     bp2.y, t43d.y, va.y, vb.y, vc.y,
                     R3.x, R3.y, R3.w, pp1, gidx), Bk1, Bk2);
      }
      {
        v2f d1   = pxB * R0.x + pyB * R0.y + pzB * R0.z + R0.w;
        v2f d2   = pxB * R1.x + pyB * R1.y + pzB * R1.z + R1.w;
        v2f ap2m = pxB * R2.x + pyB * R2.y + pzB * R2.z + R2.w;
        v2f d3 = d1 - R3.x, d6 = d2 - R3.y, d4 = d2 - R3.z, d5 = d1 - R3.z;
        v2f t43 = d4 - d3;
        v2f va = d3 * d6 - d5 * d4;
        v2f vb = d5 * d2 - d1 * d6;
        v2f vc = d1 * d4 - d3 * d2;
        v2f td1 = d1 + d1, td2 = d2 + d2;
        v2f v = vb * R4.w, w = vc * R4.w;
        v2f h1 = v * R3.x + (w * R3.z - td1);
        v2f h2 = w * R3.y + (v * R3.z - td2);
        v2f dint = ap2m + (v * h1 + w * h2);
        v2f tabm = d1 * R4.x, tacm = d2 * R4.y, tbcm = t43 * R4.z;
        v2f bp2 = (ap2m - td1) + R3.x;
        v2f t43d = t43 + t43;
        ins2(fin_one(dint.x, tabm.x, tacm.x, tbcm.x, td1.x, td2.x, ap2m.x,
                     bp2.x, t43d.x, va.x, vb.x, vc.x,
                     R3.x, R3.y, R3.w, pp2, gidx), C1, C2);
        ins2(fin_one(dint.y, tabm.y, tacm.y, tbcm.y, td1.y, td2.y, ap2m.y,
                     bp2.y, t43d.y, va.y, vb.y, vc.y,
                     R3.x, R3.y, R3.w, pp3, gidx), D1, D2);
      }
    }
  }

  keys[(size_t)chunk * NP + p0            ] = make_uint2(A1, A2);
  keys[(size_t)chunk * NP + p0 + Q/4      ] = make_uint2(Bk1, Bk2);
  keys[(size_t)chunk * NP + p0 + Q/2      ] = make_uint2(C1, C2);
  keys[(size_t)chunk * NP + p0 + 3*(Q/4)  ] = make_uint2(D1, D2);
}

// ---------------- finish: merge 2*NC keys -> top-8 -> exact ----------------

template <int NC>
__global__ __launch_bounds__(BLOCK) void bvh_finish2(
    const float* __restrict__ tris,
    const float* __restrict__ pts,
    const uint2* __restrict__ keys,
    float* __restrict__ out) {
  const int gpt = blockIdx.x * BLOCK + threadIdx.x;
  if (gpt >= NP) return;

  unsigned K1 = ~0u, K2 = ~0u, K3 = ~0u, K4 = ~0u;
  unsigned K5 = ~0u, K6 = ~0u, K7 = ~0u, K8 = ~0u;
  for (int c = 0; c < NC; ++c) {
    uint2 k = keys[(size_t)c * NP + gpt];
    ins8(k.x, K1, K2, K3, K4, K5, K6, K7, K8);
    ins8(k.y, K1, K2, K3, K4, K5, K6, K7, K8);
  }

  const int batch = gpt / Q;
  const float* tb = tris + (size_t)batch * F * 9;
  const float px = pts[gpt * 3 + 0];
  const float py = pts[gpt * 3 + 1];
  const float pz = pts[gpt * 3 + 2];

  // order-independent first-occurrence argmin over the 8 candidates
  float be = INFINITY;
  int bi = 0x7FFFFFFF;
  #define CAND(Kx) { int t_ = (int)(Kx & 0xFFFu); \
    float d_ = exact_d2(px, py, pz, tb + (size_t)t_ * 9); \
    if (d_ < be || (d_ == be && t_ < bi)) { be = d_; bi = t_; } }
  CAND(K1) CAND(K2) CAND(K3) CAND(K4) CAND(K5) CAND(K6) CAND(K7) CAND(K8)
  #undef CAND

  const float* tr = tb + (size_t)bi * 9;
  float rx, ry, rz;
  closest_pt(px, py, pz,
             tr[0], tr[1], tr[2], tr[3], tr[4], tr[5], tr[6], tr[7], tr[8],
             rx, ry, rz);

  out[OFF_DIST + gpt] = be;
  out[OFF_CP + gpt * 3 + 0] = rx;
  out[OFF_CP + gpt * 3 + 1] = ry;
  out[OFF_CP + gpt * 3 + 2] = rz;
  out[OFF_FACE + gpt] = (float)bi;
}

}  // namespace

extern "C" void kernel_launch(void* const* d_in, const int* in_sizes, int n_in,
                              void* d_out, int out_size, void* d_ws, size_t ws_size,
                              hipStream_t stream) {
  const float* tris = (const float*)d_in[0];
  const float* pts  = (const float*)d_in[1];
  float* out = (float*)d_out;

  dim3 grid2((NP + BLOCK - 1) / BLOCK);
  const int gx = B * ((Q / P4) / BLOCK);   // 32 blocks in x

  constexpr size_t KEY64_BYTES = (size_t)64 * NP * sizeof(uint2);  // 16 MiB

  if (ws_size >= KEY64_BYTES) {
    // NC=64: 2048 blocks; WPE=6 -> VGPR budget ~85 (footprint ~40-52, no spill),
    // 6 waves/SIMD vs round-10's 4.
    uint2* keys = (uint2*)d_ws;
    bvh_screen4<64, 6><<<dim3(gx, 64), BLOCK, 0, stream>>>(tris, pts, keys);
    bvh_finish2<64><<<grid2, BLOCK, 0, stream>>>(tris, pts, keys, out);
  } else {
    // round-10 proven path (8 MiB): NC=32, 4 blocks/CU
    uint2* keys = (uint2*)d_ws;
    bvh_screen4<32, 4><<<dim3(gx, 32), BLOCK, 0, stream>>>(tris, pts, keys);
    bvh_finish2<32><<<grid2, BLOCK, 0, stream>>>(tris, pts, keys, out);
  }
}